// Round 1
// 702.721 us; speedup vs baseline: 1.0688x; 1.0688x over previous
//
#include <hip/hip_runtime.h>
#include <hip/hip_bf16.h>
#include <cstdint>

// B=4, S=1024, E=1024, H=16, D=64.
// d_out = [ out (4M floats) | filtered_attn (64M floats) ].
// Pipeline: split_f32 -> gemm<0> (QKV proj, split-bf16) -> fused_attn
// (QK^T + softmax/filter + PV in one kernel, logits live in LDS only)
// -> gemm<3> (out proj).

#define BB 4
#define SS 1024
#define EE 1024
#define HH 16
#define DD 64

typedef __attribute__((ext_vector_type(8))) short bf16x8;
typedef __attribute__((ext_vector_type(4))) float f32x4;

// ---------------------------------------------------------------------------
// split cast: hi = bf16(v), lo = bf16(v - hi). lo may be null (plain cast).
// ---------------------------------------------------------------------------
__global__ __launch_bounds__(256) void split_f32(
    const float* __restrict__ in, __hip_bfloat16* __restrict__ hi,
    __hip_bfloat16* __restrict__ lo, int n4) {
  int i = blockIdx.x * 256 + threadIdx.x;
  if (i >= n4) return;
  float4 v = ((const float4*)in)[i];
  float vv[4] = {v.x, v.y, v.z, v.w};
  __hip_bfloat16 h[4], l[4];
#pragma unroll
  for (int j = 0; j < 4; ++j) {
    h[j] = __float2bfloat16(vv[j]);
    l[j] = __float2bfloat16(vv[j] - __bfloat162float(h[j]));
  }
  ((ushort4*)hi)[i] = *(ushort4*)h;
  if (lo) ((ushort4*)lo)[i] = *(ushort4*)l;
}

// ---------------------------------------------------------------------------
// NT GEMM: C[m][n] = sum_k A[m*lda+k]*B[n*ldb+k]. 128x128 tile, BK=64,
// 4 waves (2x2), 4x4 x 16x16x32 bf16 MFMA per wave.
// MODE 0 (SPLIT): A=(xh,xl) B=(Wqh,Wql); +bias(f32); out: qh,ql,kh,kl [B,H,S,D], vT [B,H,D,S]
// MODE 3: A=ao B=Wproj_h; +bias(f32); out fp32 oF[m*E+n]
// ---------------------------------------------------------------------------
template <int MODE>
__global__ __launch_bounds__(256) void gemm(
    const __hip_bfloat16* __restrict__ Ah, const __hip_bfloat16* __restrict__ Al,
    const __hip_bfloat16* __restrict__ Bh, const __hip_bfloat16* __restrict__ Bl,
    const float* __restrict__ Af, const float* __restrict__ bias,
    float* __restrict__ oF, __hip_bfloat16* __restrict__ o1,
    __hip_bfloat16* __restrict__ o2, __hip_bfloat16* __restrict__ o3,
    __hip_bfloat16* __restrict__ o4, __hip_bfloat16* __restrict__ o5,
    int M, int N, int K, int lda, int ldb, long long sA, long long sB) {
  constexpr bool SPLIT = (MODE == 0 || MODE == 1);
  constexpr bool AF32  = (MODE == 2);

  const int tid  = threadIdx.x;
  const int lane = tid & 63;
  const int wave = tid >> 6;
  const int wm   = (wave >> 1) * 64;
  const int wn   = (wave & 1) * 64;
  const int quad = lane >> 4;
  const int l15  = lane & 15;
  const int m0   = blockIdx.y * 128;
  const int n0   = blockIdx.x * 128;
  const long long zz = blockIdx.z;

  if (AF32) Af += zz * sA;
  else { Ah += zz * sA; if (SPLIT) Al += zz * sA; }
  Bh += zz * sB;
  if (SPLIT) Bl += zz * sB;

  __shared__ __align__(16) __hip_bfloat16 lds[(SPLIT ? 4 : 2) * 128 * 72];
  __hip_bfloat16* lAh = lds;
  __hip_bfloat16* lAl = SPLIT ? lds + 128 * 72 : nullptr;
  __hip_bfloat16* lBh = lds + (SPLIT ? 2 : 1) * 128 * 72;
  __hip_bfloat16* lBl = SPLIT ? lds + 3 * 128 * 72 : nullptr;

  f32x4 acc[4][4] = {};

  for (int k0 = 0; k0 < K; k0 += 64) {
#pragma unroll
    for (int it = 0; it < 4; ++it) {
      int flat = (it * 256 + tid) * 8;
      int row  = flat >> 6;
      int kk   = flat & 63;
      const bool mok = (m0 + row < M);
      const bool nok = (n0 + row < N);
      if (AF32) {
        float4 f0 = {0, 0, 0, 0}, f1 = {0, 0, 0, 0};
        if (mok) {
          const float* src = Af + (long long)(m0 + row) * lda + k0 + kk;
          f0 = *(const float4*)src;
          f1 = *(const float4*)(src + 4);
        }
        __hip_bfloat16 t[8];
        t[0] = __float2bfloat16(f0.x); t[1] = __float2bfloat16(f0.y);
        t[2] = __float2bfloat16(f0.z); t[3] = __float2bfloat16(f0.w);
        t[4] = __float2bfloat16(f1.x); t[5] = __float2bfloat16(f1.y);
        t[6] = __float2bfloat16(f1.z); t[7] = __float2bfloat16(f1.w);
        *(uint4*)&lAh[row * 72 + kk] = *(uint4*)t;
      } else {
        uint4 va = {0, 0, 0, 0};
        if (mok) va = *(const uint4*)(Ah + (long long)(m0 + row) * lda + k0 + kk);
        *(uint4*)&lAh[row * 72 + kk] = va;
        if (SPLIT) {
          uint4 vl = {0, 0, 0, 0};
          if (mok) vl = *(const uint4*)(Al + (long long)(m0 + row) * lda + k0 + kk);
          *(uint4*)&lAl[row * 72 + kk] = vl;
        }
      }
      uint4 vb = {0, 0, 0, 0};
      if (nok) vb = *(const uint4*)(Bh + (long long)(n0 + row) * ldb + k0 + kk);
      *(uint4*)&lBh[row * 72 + kk] = vb;
      if (SPLIT) {
        uint4 vbl = {0, 0, 0, 0};
        if (nok) vbl = *(const uint4*)(Bl + (long long)(n0 + row) * ldb + k0 + kk);
        *(uint4*)&lBl[row * 72 + kk] = vbl;
      }
    }
    __syncthreads();

#pragma unroll
    for (int ks = 0; ks < 64; ks += 32) {
      bf16x8 ah[4], bh[4], al[4], bl[4];
#pragma unroll
      for (int i = 0; i < 4; ++i) {
        int off = (wm + i * 16 + l15) * 72 + ks + quad * 8;
        ah[i] = *(const bf16x8*)&lAh[off];
        if (SPLIT) al[i] = *(const bf16x8*)&lAl[off];
      }
#pragma unroll
      for (int j = 0; j < 4; ++j) {
        int off = (wn + j * 16 + l15) * 72 + ks + quad * 8;
        bh[j] = *(const bf16x8*)&lBh[off];
        if (SPLIT) bl[j] = *(const bf16x8*)&lBl[off];
      }
#pragma unroll
      for (int i = 0; i < 4; ++i)
#pragma unroll
        for (int j = 0; j < 4; ++j) {
          if (SPLIT) {
            acc[i][j] = __builtin_amdgcn_mfma_f32_16x16x32_bf16(al[i], bh[j], acc[i][j], 0, 0, 0);
            acc[i][j] = __builtin_amdgcn_mfma_f32_16x16x32_bf16(ah[i], bl[j], acc[i][j], 0, 0, 0);
          }
          acc[i][j] = __builtin_amdgcn_mfma_f32_16x16x32_bf16(ah[i], bh[j], acc[i][j], 0, 0, 0);
        }
    }
    __syncthreads();
  }

  // C/D layout: col = lane&15, row = quad*4 + reg
#pragma unroll
  for (int i = 0; i < 4; ++i) {
#pragma unroll
    for (int j = 0; j < 4; ++j) {
#pragma unroll
      for (int r = 0; r < 4; ++r) {
        int m = m0 + wm + i * 16 + quad * 4 + r;
        int n = n0 + wn + j * 16 + l15;
        float v = acc[i][j][r];
        if (MODE == 0) {
          v += bias[n];
          int c = n >> 10, nn = n & 1023, h = nn >> 6, d = nn & 63;
          int b = m >> 10, s = m & 1023;
          long long idx = (((long long)(b * HH + h) * SS + s) << 6) + d;
          if (c == 0) {
            __hip_bfloat16 hh = __float2bfloat16(v);
            o1[idx] = hh;
            o2[idx] = __float2bfloat16(v - __bfloat162float(hh));
          } else if (c == 1) {
            __hip_bfloat16 hh = __float2bfloat16(v);
            o3[idx] = hh;
            o4[idx] = __float2bfloat16(v - __bfloat162float(hh));
          } else {
            o5[(((long long)(b * HH + h) * DD + d) << 10) + s] = __float2bfloat16(v);
          }
        } else if (MODE == 1) {
          oF[zz * (SS * SS) + (long long)m * SS + n] = v * 0.125f;
        } else if (MODE == 2) {
          if (n < DD) {
            int b = (int)(zz >> 4), h = (int)(zz & 15);
            o1[(((long long)(b * SS + m)) << 10) + h * DD + n] = __float2bfloat16(v);
          }
        } else {
          oF[(long long)m * EE + n] = v + bias[n];
        }
      }
    }
  }
}

// ---------------------------------------------------------------------------
// wave reductions
// ---------------------------------------------------------------------------
__device__ __forceinline__ float wave_max64(float v) {
#pragma unroll
  for (int o = 32; o > 0; o >>= 1) v = fmaxf(v, __shfl_xor(v, o));
  return v;
}
__device__ __forceinline__ float wave_sum64(float v) {
#pragma unroll
  for (int o = 32; o > 0; o >>= 1) v += __shfl_xor(v, o);
  return v;
}

// ---------------------------------------------------------------------------
// fused_attn: one block per (bh, 16-row Q strip). 4 waves / 256 threads.
// Phase 1 (QK^T): wave w computes logit cols [w*256, w*256+256) for all 16 Q
//   rows via split-bf16 MFMA (A=Q frags in regs, B=K frags direct from L2),
//   stores fp32 logits*0.125 into LDS lg[16][1032].
// Phase 2 (softmax/filter): wave w owns rows w*4..w*4+3. Lane reads 16
//   strided floats (conflict-free), wave-reduce m/Z/Zs exactly as the old
//   softmax_filter, writes filtered probs fp32 -> global attn (the required
//   output, written ONCE) and bf16 -> LDS in place (P for PV). Safe without
//   extra sync: every P store data-depends on all 16 logit loads via Zs.
// Phase 3 (PV): out[16q x 64d] = P[16x1024] @ V; wave w owns d-cols
//   [w*16,+16); A=P frags from LDS, B=vT frags direct from L2.
// LDS = 66 KB -> 2 blocks/CU. Logits never touch HBM.
// ---------------------------------------------------------------------------
__global__ __launch_bounds__(256) void fused_attn(
    const __hip_bfloat16* __restrict__ qh, const __hip_bfloat16* __restrict__ ql,
    const __hip_bfloat16* __restrict__ kh, const __hip_bfloat16* __restrict__ kl,
    const __hip_bfloat16* __restrict__ vT, float* __restrict__ attn,
    __hip_bfloat16* __restrict__ ao) {
  const int tid  = threadIdx.x;
  const int lane = tid & 63;
  const int wave = tid >> 6;
  const int quad = lane >> 4;
  const int l15  = lane & 15;
  const int bh   = blockIdx.y;
  const int q0   = blockIdx.x * 16;
  const int brow = (bh >> 4) * SS;   // 0 in per-batch mode (bh = h < 16)
  const int h    = bh & 15;
  const long long qbase = ((long long)bh * SS + q0) * DD;
  const long long kbase = (long long)bh * SS * DD;
  const long long vbase = (long long)bh * DD * SS;
  const long long abase = ((long long)bh * SS + q0) * SS;

  __shared__ __align__(16) float lg[16][1032];

  // --- Q A-frags (row l15, k-cols ks*32 + quad*8), hi & lo ---
  bf16x8 aqh[2], aql[2];
  {
    const __hip_bfloat16* ph = qh + qbase + l15 * DD + quad * 8;
    const __hip_bfloat16* pl = ql + qbase + l15 * DD + quad * 8;
    aqh[0] = *(const bf16x8*)(ph);
    aqh[1] = *(const bf16x8*)(ph + 32);
    aql[0] = *(const bf16x8*)(pl);
    aql[1] = *(const bf16x8*)(pl + 32);
  }

  // --- Phase 1: QK^T ---
#pragma unroll
  for (int nt = 0; nt < 16; ++nt) {
    const int n = wave * 256 + nt * 16;
    const __hip_bfloat16* pkh = kh + kbase + (long long)(n + l15) * DD + quad * 8;
    const __hip_bfloat16* pkl = kl + kbase + (long long)(n + l15) * DD + quad * 8;
    bf16x8 bh0 = *(const bf16x8*)(pkh);
    bf16x8 bh1 = *(const bf16x8*)(pkh + 32);
    bf16x8 bl0 = *(const bf16x8*)(pkl);
    bf16x8 bl1 = *(const bf16x8*)(pkl + 32);
    f32x4 acc = {};
    acc = __builtin_amdgcn_mfma_f32_16x16x32_bf16(aql[0], bh0, acc, 0, 0, 0);
    acc = __builtin_amdgcn_mfma_f32_16x16x32_bf16(aqh[0], bl0, acc, 0, 0, 0);
    acc = __builtin_amdgcn_mfma_f32_16x16x32_bf16(aqh[0], bh0, acc, 0, 0, 0);
    acc = __builtin_amdgcn_mfma_f32_16x16x32_bf16(aql[1], bh1, acc, 0, 0, 0);
    acc = __builtin_amdgcn_mfma_f32_16x16x32_bf16(aqh[1], bl1, acc, 0, 0, 0);
    acc = __builtin_amdgcn_mfma_f32_16x16x32_bf16(aqh[1], bh1, acc, 0, 0, 0);
    // C: row(q) = quad*4+r, col(kpos) = l15
#pragma unroll
    for (int r = 0; r < 4; ++r) lg[quad * 4 + r][n + l15] = acc[r] * 0.125f;
  }
  __syncthreads();

  // --- Phase 2: softmax + threshold filter (identical math to old kernel) ---
#pragma unroll
  for (int rr = 0; rr < 4; ++rr) {
    const int row = wave * 4 + rr;
    float v[16];
#pragma unroll
    for (int i = 0; i < 16; ++i) v[i] = lg[row][lane + i * 64];
    float mloc = v[0];
#pragma unroll
    for (int t = 1; t < 16; ++t) mloc = fmaxf(mloc, v[t]);
    const float m = wave_max64(mloc);
    float e[16], zloc = 0.f;
#pragma unroll
    for (int t = 0; t < 16; ++t) { e[t] = expf(v[t] - m); zloc += e[t]; }
    const float Z = wave_sum64(zloc);
    float zsloc = 0.f;
    bool sel[16];
#pragma unroll
    for (int t = 0; t < 16; ++t) {
      sel[t] = (e[t] / Z) > 4e-4f;
      if (sel[t]) zsloc += e[t];
    }
    const float Zs = wave_sum64(zsloc);
    float* arow = attn + abase + (long long)row * SS;
    __hip_bfloat16* prow = (__hip_bfloat16*)&lg[row][0];
#pragma unroll
    for (int i = 0; i < 16; ++i) {
      const float w = sel[i] ? e[i] / Zs : 0.f;
      arow[lane + i * 64] = w;                      // required output, fp32
      prow[lane + i * 64] = __float2bfloat16(w);    // P for PV, in place
    }
  }
  __syncthreads();

  // --- Phase 3: PV. wave owns d-cols [wave*16, +16) ---
  const int d0 = wave * 16;
  f32x4 oacc = {};
  const __hip_bfloat16* pv = vT + vbase + (long long)(d0 + l15) * SS + quad * 8;
  const __hip_bfloat16* pp = (const __hip_bfloat16*)&lg[l15][0] + quad * 8;
#pragma unroll
  for (int ks = 0; ks < 32; ++ks) {
    bf16x8 ap = *(const bf16x8*)(pp + ks * 32);
    bf16x8 bv = *(const bf16x8*)(pv + ks * 32);
    oacc = __builtin_amdgcn_mfma_f32_16x16x32_bf16(ap, bv, oacc, 0, 0, 0);
  }
  // C: row(q) = quad*4+r, col(d) = l15
#pragma unroll
  for (int r = 0; r < 4; ++r) {
    const int q = q0 + quad * 4 + r;
    ao[((long long)(brow + q)) * EE + h * DD + d0 + l15] = __float2bfloat16(oacc[r]);
  }
}

// ---------------------------------------------------------------------------
extern "C" void kernel_launch(void* const* d_in, const int* in_sizes, int n_in,
                              void* d_out, int out_size, void* d_ws, size_t ws_size,
                              hipStream_t stream) {
  const float* x     = (const float*)d_in[0];  // [4,1024,1024]
  const float* Wqkv  = (const float*)d_in[1];  // [3072,1024]
  const float* bqkv  = (const float*)d_in[2];  // [3072]
  const float* Wproj = (const float*)d_in[3];  // [1024,1024]
  const float* bproj = (const float*)d_in[4];  // [1024]

  float* out   = (float*)d_out;                        // 4M floats
  float* attnF = out + (size_t)BB * SS * EE;           // 64M floats

  const size_t M1 = 1024 * 1024;
  __hip_bfloat16* w = (__hip_bfloat16*)d_ws;

  if (ws_size >= (size_t)80 * 1024 * 1024) {
    // flat: 39M bf16 elems = 78MB
    __hip_bfloat16 *xh = w, *xl = xh + 4 * M1;
    __hip_bfloat16 *Wqh = xl + 4 * M1, *Wql = Wqh + 3 * M1, *Wph = Wql + 3 * M1;
    __hip_bfloat16 *qh = Wph + M1, *ql = qh + 4 * M1, *kh = ql + 4 * M1, *kl = kh + 4 * M1;
    __hip_bfloat16 *vT = kl + 4 * M1, *ao = vT + 4 * M1;

    split_f32<<<4096, 256, 0, stream>>>(x, xh, xl, 1024 * 1024);
    split_f32<<<3072, 256, 0, stream>>>(Wqkv, Wqh, Wql, 768 * 1024);
    split_f32<<<1024, 256, 0, stream>>>(Wproj, Wph, nullptr, 256 * 1024);

    gemm<0><<<dim3(24, 32, 1), 256, 0, stream>>>(
        xh, xl, Wqh, Wql, nullptr, bqkv, nullptr, qh, ql, kh, kl, vT,
        4096, 3072, 1024, 1024, 1024, 0LL, 0LL);
    fused_attn<<<dim3(SS / 16, BB * HH), 256, 0, stream>>>(
        qh, ql, kh, kl, vT, attnF, ao);
    gemm<3><<<dim3(8, 32, 1), 256, 0, stream>>>(
        ao, nullptr, Wph, nullptr, nullptr, bproj, out, nullptr, nullptr, nullptr, nullptr, nullptr,
        4096, 1024, 1024, 1024, 1024, 0LL, 0LL);
    return;
  }

  // per-batch: 7M shared + 8M per-batch = 15M elems = 30MB
  __hip_bfloat16 *Wqh = w, *Wql = Wqh + 3 * M1, *Wph = Wql + 3 * M1;
  __hip_bfloat16 *xh = Wph + M1, *xl = xh + M1;
  __hip_bfloat16 *qh = xl + M1, *ql = qh + M1, *kh = ql + M1, *kl = kh + M1;
  __hip_bfloat16 *vT = kl + M1, *ao = vT + M1;

  split_f32<<<3072, 256, 0, stream>>>(Wqkv, Wqh, Wql, 768 * 1024);
  split_f32<<<1024, 256, 0, stream>>>(Wproj, Wph, nullptr, 256 * 1024);

  for (int b = 0; b < BB; ++b) {
    const float* xb   = x + (size_t)b * SS * EE;
    float* attnb      = attnF + (size_t)b * HH * SS * SS;
    float* outb       = out + (size_t)b * SS * EE;

    split_f32<<<1024, 256, 0, stream>>>(xb, xh, xl, 256 * 1024);
    gemm<0><<<dim3(24, 8, 1), 256, 0, stream>>>(
        xh, xl, Wqh, Wql, nullptr, bqkv, nullptr, qh, ql, kh, kl, vT,
        1024, 3072, 1024, 1024, 1024, 0LL, 0LL);
    fused_attn<<<dim3(SS / 16, HH), 256, 0, stream>>>(
        qh, ql, kh, kl, vT, attnb, ao);
    gemm<3><<<dim3(8, 8, 1), 256, 0, stream>>>(
        ao, nullptr, Wph, nullptr, nullptr, bproj, outb, nullptr, nullptr, nullptr, nullptr, nullptr,
        1024, 1024, 1024, 1024, 1024, 0LL, 0LL);
  }
}

// Round 2
// 691.527 us; speedup vs baseline: 1.0861x; 1.0162x over previous
//
#include <hip/hip_runtime.h>
#include <hip/hip_bf16.h>
#include <cstdint>

// B=4, S=1024, E=1024, H=16, D=64.
// d_out = [ out (4M floats) | filtered_attn (64M floats) ].
// Pipeline: split_f32 -> gemm<0> (QKV proj, split-bf16) -> fused_attn
// (QK^T + softmax/filter + PV; logits REGISTER-resident, only bf16 P in LDS)
// -> gemm<3> (out proj).

#define BB 4
#define SS 1024
#define EE 1024
#define HH 16
#define DD 64

typedef __attribute__((ext_vector_type(8))) short bf16x8;
typedef __attribute__((ext_vector_type(4))) float f32x4;

// ---------------------------------------------------------------------------
// split cast: hi = bf16(v), lo = bf16(v - hi). lo may be null (plain cast).
// ---------------------------------------------------------------------------
__global__ __launch_bounds__(256) void split_f32(
    const float* __restrict__ in, __hip_bfloat16* __restrict__ hi,
    __hip_bfloat16* __restrict__ lo, int n4) {
  int i = blockIdx.x * 256 + threadIdx.x;
  if (i >= n4) return;
  float4 v = ((const float4*)in)[i];
  float vv[4] = {v.x, v.y, v.z, v.w};
  __hip_bfloat16 h[4], l[4];
#pragma unroll
  for (int j = 0; j < 4; ++j) {
    h[j] = __float2bfloat16(vv[j]);
    l[j] = __float2bfloat16(vv[j] - __bfloat162float(h[j]));
  }
  ((ushort4*)hi)[i] = *(ushort4*)h;
  if (lo) ((ushort4*)lo)[i] = *(ushort4*)l;
}

// ---------------------------------------------------------------------------
// NT GEMM: C[m][n] = sum_k A[m*lda+k]*B[n*ldb+k]. 128x128 tile, BK=64,
// 4 waves (2x2), 4x4 x 16x16x32 bf16 MFMA per wave.
// MODE 0 (SPLIT): A=(xh,xl) B=(Wqh,Wql); +bias(f32); out: qh,ql,kh,kl [B,H,S,D], vT [B,H,D,S]
// MODE 3: A=ao B=Wproj_h; +bias(f32); out fp32 oF[m*E+n]
// ---------------------------------------------------------------------------
template <int MODE>
__global__ __launch_bounds__(256) void gemm(
    const __hip_bfloat16* __restrict__ Ah, const __hip_bfloat16* __restrict__ Al,
    const __hip_bfloat16* __restrict__ Bh, const __hip_bfloat16* __restrict__ Bl,
    const float* __restrict__ Af, const float* __restrict__ bias,
    float* __restrict__ oF, __hip_bfloat16* __restrict__ o1,
    __hip_bfloat16* __restrict__ o2, __hip_bfloat16* __restrict__ o3,
    __hip_bfloat16* __restrict__ o4, __hip_bfloat16* __restrict__ o5,
    int M, int N, int K, int lda, int ldb, long long sA, long long sB) {
  constexpr bool SPLIT = (MODE == 0 || MODE == 1);
  constexpr bool AF32  = (MODE == 2);

  const int tid  = threadIdx.x;
  const int lane = tid & 63;
  const int wave = tid >> 6;
  const int wm   = (wave >> 1) * 64;
  const int wn   = (wave & 1) * 64;
  const int quad = lane >> 4;
  const int l15  = lane & 15;
  const int m0   = blockIdx.y * 128;
  const int n0   = blockIdx.x * 128;
  const long long zz = blockIdx.z;

  if (AF32) Af += zz * sA;
  else { Ah += zz * sA; if (SPLIT) Al += zz * sA; }
  Bh += zz * sB;
  if (SPLIT) Bl += zz * sB;

  __shared__ __align__(16) __hip_bfloat16 lds[(SPLIT ? 4 : 2) * 128 * 72];
  __hip_bfloat16* lAh = lds;
  __hip_bfloat16* lAl = SPLIT ? lds + 128 * 72 : nullptr;
  __hip_bfloat16* lBh = lds + (SPLIT ? 2 : 1) * 128 * 72;
  __hip_bfloat16* lBl = SPLIT ? lds + 3 * 128 * 72 : nullptr;

  f32x4 acc[4][4] = {};

  for (int k0 = 0; k0 < K; k0 += 64) {
#pragma unroll
    for (int it = 0; it < 4; ++it) {
      int flat = (it * 256 + tid) * 8;
      int row  = flat >> 6;
      int kk   = flat & 63;
      const bool mok = (m0 + row < M);
      const bool nok = (n0 + row < N);
      if (AF32) {
        float4 f0 = {0, 0, 0, 0}, f1 = {0, 0, 0, 0};
        if (mok) {
          const float* src = Af + (long long)(m0 + row) * lda + k0 + kk;
          f0 = *(const float4*)src;
          f1 = *(const float4*)(src + 4);
        }
        __hip_bfloat16 t[8];
        t[0] = __float2bfloat16(f0.x); t[1] = __float2bfloat16(f0.y);
        t[2] = __float2bfloat16(f0.z); t[3] = __float2bfloat16(f0.w);
        t[4] = __float2bfloat16(f1.x); t[5] = __float2bfloat16(f1.y);
        t[6] = __float2bfloat16(f1.z); t[7] = __float2bfloat16(f1.w);
        *(uint4*)&lAh[row * 72 + kk] = *(uint4*)t;
      } else {
        uint4 va = {0, 0, 0, 0};
        if (mok) va = *(const uint4*)(Ah + (long long)(m0 + row) * lda + k0 + kk);
        *(uint4*)&lAh[row * 72 + kk] = va;
        if (SPLIT) {
          uint4 vl = {0, 0, 0, 0};
          if (mok) vl = *(const uint4*)(Al + (long long)(m0 + row) * lda + k0 + kk);
          *(uint4*)&lAl[row * 72 + kk] = vl;
        }
      }
      uint4 vb = {0, 0, 0, 0};
      if (nok) vb = *(const uint4*)(Bh + (long long)(n0 + row) * ldb + k0 + kk);
      *(uint4*)&lBh[row * 72 + kk] = vb;
      if (SPLIT) {
        uint4 vbl = {0, 0, 0, 0};
        if (nok) vbl = *(const uint4*)(Bl + (long long)(n0 + row) * ldb + k0 + kk);
        *(uint4*)&lBl[row * 72 + kk] = vbl;
      }
    }
    __syncthreads();

#pragma unroll
    for (int ks = 0; ks < 64; ks += 32) {
      bf16x8 ah[4], bh[4], al[4], bl[4];
#pragma unroll
      for (int i = 0; i < 4; ++i) {
        int off = (wm + i * 16 + l15) * 72 + ks + quad * 8;
        ah[i] = *(const bf16x8*)&lAh[off];
        if (SPLIT) al[i] = *(const bf16x8*)&lAl[off];
      }
#pragma unroll
      for (int j = 0; j < 4; ++j) {
        int off = (wn + j * 16 + l15) * 72 + ks + quad * 8;
        bh[j] = *(const bf16x8*)&lBh[off];
        if (SPLIT) bl[j] = *(const bf16x8*)&lBl[off];
      }
#pragma unroll
      for (int i = 0; i < 4; ++i)
#pragma unroll
        for (int j = 0; j < 4; ++j) {
          if (SPLIT) {
            acc[i][j] = __builtin_amdgcn_mfma_f32_16x16x32_bf16(al[i], bh[j], acc[i][j], 0, 0, 0);
            acc[i][j] = __builtin_amdgcn_mfma_f32_16x16x32_bf16(ah[i], bl[j], acc[i][j], 0, 0, 0);
          }
          acc[i][j] = __builtin_amdgcn_mfma_f32_16x16x32_bf16(ah[i], bh[j], acc[i][j], 0, 0, 0);
        }
    }
    __syncthreads();
  }

  // C/D layout: col = lane&15, row = quad*4 + reg
#pragma unroll
  for (int i = 0; i < 4; ++i) {
#pragma unroll
    for (int j = 0; j < 4; ++j) {
#pragma unroll
      for (int r = 0; r < 4; ++r) {
        int m = m0 + wm + i * 16 + quad * 4 + r;
        int n = n0 + wn + j * 16 + l15;
        float v = acc[i][j][r];
        if (MODE == 0) {
          v += bias[n];
          int c = n >> 10, nn = n & 1023, h = nn >> 6, d = nn & 63;
          int b = m >> 10, s = m & 1023;
          long long idx = (((long long)(b * HH + h) * SS + s) << 6) + d;
          if (c == 0) {
            __hip_bfloat16 hh = __float2bfloat16(v);
            o1[idx] = hh;
            o2[idx] = __float2bfloat16(v - __bfloat162float(hh));
          } else if (c == 1) {
            __hip_bfloat16 hh = __float2bfloat16(v);
            o3[idx] = hh;
            o4[idx] = __float2bfloat16(v - __bfloat162float(hh));
          } else {
            o5[(((long long)(b * HH + h) * DD + d) << 10) + s] = __float2bfloat16(v);
          }
        } else if (MODE == 1) {
          oF[zz * (SS * SS) + (long long)m * SS + n] = v * 0.125f;
        } else if (MODE == 2) {
          if (n < DD) {
            int b = (int)(zz >> 4), h = (int)(zz & 15);
            o1[(((long long)(b * SS + m)) << 10) + h * DD + n] = __float2bfloat16(v);
          }
        } else {
          oF[(long long)m * EE + n] = v + bias[n];
        }
      }
    }
  }
}

// ---------------------------------------------------------------------------
// 16-lane-group reductions (lanes quad*16 .. quad*16+15; xor<=8 stays in group)
// ---------------------------------------------------------------------------
__device__ __forceinline__ float qg_max16(float v) {
#pragma unroll
  for (int o = 8; o > 0; o >>= 1) v = fmaxf(v, __shfl_xor(v, o));
  return v;
}
__device__ __forceinline__ float qg_sum16(float v) {
#pragma unroll
  for (int o = 8; o > 0; o >>= 1) v += __shfl_xor(v, o);
  return v;
}

// ---------------------------------------------------------------------------
// fused_attn v2: one block per (bh, 16-row Q strip). 4 waves / 256 threads.
// Logits are REGISTER-resident: wave w owns k-cols [w*256, w*256+256) ->
// acc[16] f32x4 (64 VGPR). lane (quad,l15) holds (q=quad*4+r, k=w*256+nt*16+l15).
// Softmax reductions: lane-local over nt -> shfl over l15 group -> tiny LDS
// cross-wave combine (red[3][4][16], 768 B, 3 syncs).
// Filter is division-free: sel = e > (4e-4*Z); P = sel ? e*(1/Zs) : 0.
// P written once to global attn (f32) and to LDS bf16 tile Pl[16][1032]
// (pad 8 bf16 -> stride 516 dwords == 4 mod 32 -> phase-3 b128 reads 2-way/free).
// Phase 3 PV: A=P from LDS, B=vT from L2, two independent MFMA chains.
// LDS 33.3 KB + VGPR<=128 (__launch_bounds__(256,4)) -> 4 blocks/CU (16 waves).
// XCD-chunked block swizzle keeps same-head blocks on one XCD's L2.
// ---------------------------------------------------------------------------
__global__ __launch_bounds__(256, 4) void fused_attn(
    const __hip_bfloat16* __restrict__ qh, const __hip_bfloat16* __restrict__ ql,
    const __hip_bfloat16* __restrict__ kh, const __hip_bfloat16* __restrict__ kl,
    const __hip_bfloat16* __restrict__ vT, float* __restrict__ attn,
    __hip_bfloat16* __restrict__ ao) {
  const int tid  = threadIdx.x;
  const int lane = tid & 63;
  const int wave = tid >> 6;
  const int quad = lane >> 4;
  const int l15  = lane & 15;

  // XCD-chunked swizzle (gridDim.x is a multiple of 8 -> bijective)
  int id = blockIdx.x;
  const int q8 = gridDim.x >> 3;
  id = (id & 7) * q8 + (id >> 3);
  const int bh = id >> 6;
  const int q0 = (id & 63) * 16;

  const int brow = (bh >> 4) * SS;   // 0 in per-batch mode (bh = h < 16)
  const int h    = bh & 15;
  const long long qbase = ((long long)bh * SS + q0) * DD;
  const long long kbase = (long long)bh * SS * DD;
  const long long vbase = (long long)bh * DD * SS;
  const long long abase = ((long long)bh * SS + q0) * SS;

  __shared__ __align__(16) __hip_bfloat16 Pl[16][1032];  // 33,024 B
  __shared__ float red[3][4][16];                        // 768 B

  // --- Q A-frags (row l15, k-cols quad*8 (+32)), hi & lo ---
  bf16x8 aqh0, aqh1, aql0, aql1;
  {
    const __hip_bfloat16* ph = qh + qbase + l15 * DD + quad * 8;
    const __hip_bfloat16* pl = ql + qbase + l15 * DD + quad * 8;
    aqh0 = *(const bf16x8*)(ph);
    aqh1 = *(const bf16x8*)(ph + 32);
    aql0 = *(const bf16x8*)(pl);
    aql1 = *(const bf16x8*)(pl + 32);
  }

  // --- Phase 1: QK^T, register-resident ---
  f32x4 acc[16];
  const __hip_bfloat16* pkh0 = kh + kbase + (long long)(wave * 256 + l15) * DD + quad * 8;
  const __hip_bfloat16* pkl0 = kl + kbase + (long long)(wave * 256 + l15) * DD + quad * 8;
#pragma unroll
  for (int nt = 0; nt < 16; ++nt) {
    const __hip_bfloat16* pkh = pkh0 + nt * 16 * DD;
    const __hip_bfloat16* pkl = pkl0 + nt * 16 * DD;
    bf16x8 b0 = *(const bf16x8*)(pkh);
    bf16x8 b1 = *(const bf16x8*)(pkh + 32);
    bf16x8 c0 = *(const bf16x8*)(pkl);
    bf16x8 c1 = *(const bf16x8*)(pkl + 32);
    f32x4 a = {};
    a = __builtin_amdgcn_mfma_f32_16x16x32_bf16(aql0, b0, a, 0, 0, 0);
    a = __builtin_amdgcn_mfma_f32_16x16x32_bf16(aqh0, c0, a, 0, 0, 0);
    a = __builtin_amdgcn_mfma_f32_16x16x32_bf16(aqh0, b0, a, 0, 0, 0);
    a = __builtin_amdgcn_mfma_f32_16x16x32_bf16(aql1, b1, a, 0, 0, 0);
    a = __builtin_amdgcn_mfma_f32_16x16x32_bf16(aqh1, c1, a, 0, 0, 0);
    a = __builtin_amdgcn_mfma_f32_16x16x32_bf16(aqh1, b1, a, 0, 0, 0);
    acc[nt] = a;
  }

  // scale by 1/8 (D=64 -> D^-0.5)
#pragma unroll
  for (int nt = 0; nt < 16; ++nt)
#pragma unroll
    for (int r = 0; r < 4; ++r) acc[nt][r] *= 0.125f;

  // --- row max: lane-local over nt -> l15-group -> cross-wave ---
  float mx[4];
#pragma unroll
  for (int r = 0; r < 4; ++r) {
    float mm = acc[0][r];
#pragma unroll
    for (int nt = 1; nt < 16; ++nt) mm = fmaxf(mm, acc[nt][r]);
    mx[r] = qg_max16(mm);
  }
  if (l15 == 0) {
#pragma unroll
    for (int r = 0; r < 4; ++r) red[0][wave][quad * 4 + r] = mx[r];
  }
  __syncthreads();
  float m[4];
#pragma unroll
  for (int r = 0; r < 4; ++r) {
    const int q = quad * 4 + r;
    m[r] = fmaxf(fmaxf(red[0][0][q], red[0][1][q]),
                 fmaxf(red[0][2][q], red[0][3][q]));
  }

  // --- e = exp(v - m), Z ---
  float zl[4] = {0.f, 0.f, 0.f, 0.f};
#pragma unroll
  for (int nt = 0; nt < 16; ++nt)
#pragma unroll
    for (int r = 0; r < 4; ++r) {
      float e = expf(acc[nt][r] - m[r]);
      acc[nt][r] = e;
      zl[r] += e;
    }
#pragma unroll
  for (int r = 0; r < 4; ++r) zl[r] = qg_sum16(zl[r]);
  if (l15 == 0) {
#pragma unroll
    for (int r = 0; r < 4; ++r) red[1][wave][quad * 4 + r] = zl[r];
  }
  __syncthreads();
  float c[4];
#pragma unroll
  for (int r = 0; r < 4; ++r) {
    const int q = quad * 4 + r;
    const float Z = (red[1][0][q] + red[1][1][q]) + (red[1][2][q] + red[1][3][q]);
    c[r] = 4e-4f * Z;   // sel: e > c  <=>  e/Z > 4e-4
  }

  // --- Zs = sum of selected e ---
  float sl[4] = {0.f, 0.f, 0.f, 0.f};
#pragma unroll
  for (int nt = 0; nt < 16; ++nt)
#pragma unroll
    for (int r = 0; r < 4; ++r)
      if (acc[nt][r] > c[r]) sl[r] += acc[nt][r];
#pragma unroll
  for (int r = 0; r < 4; ++r) sl[r] = qg_sum16(sl[r]);
  if (l15 == 0) {
#pragma unroll
    for (int r = 0; r < 4; ++r) red[2][wave][quad * 4 + r] = sl[r];
  }
  __syncthreads();
  float rinv[4];
#pragma unroll
  for (int r = 0; r < 4; ++r) {
    const int q = quad * 4 + r;
    const float Zs = (red[2][0][q] + red[2][1][q]) + (red[2][2][q] + red[2][3][q]);
    rinv[r] = 1.0f / Zs;   // row max always selected -> Zs >= 1
  }

  // --- write filtered probs: f32 -> global (required), bf16 -> LDS (P) ---
#pragma unroll
  for (int nt = 0; nt < 16; ++nt) {
    const int k = wave * 256 + nt * 16 + l15;
#pragma unroll
    for (int r = 0; r < 4; ++r) {
      const int q = quad * 4 + r;
      const float e = acc[nt][r];
      const float p = (e > c[r]) ? e * rinv[r] : 0.f;
      attn[abase + (long long)q * SS + k] = p;
      Pl[q][k] = __float2bfloat16(p);
    }
  }
  __syncthreads();

  // --- Phase 3: PV. wave owns d-cols [wave*16, +16); 2 indep MFMA chains ---
  const int d0 = wave * 16;
  f32x4 o0 = {}, o1 = {};
  const __hip_bfloat16* pv = vT + vbase + (long long)(d0 + l15) * SS + quad * 8;
  const __hip_bfloat16* pp = &Pl[l15][0] + quad * 8;
#pragma unroll
  for (int ks = 0; ks < 32; ks += 2) {
    bf16x8 a0 = *(const bf16x8*)(pp + ks * 32);
    bf16x8 v0 = *(const bf16x8*)(pv + ks * 32);
    o0 = __builtin_amdgcn_mfma_f32_16x16x32_bf16(a0, v0, o0, 0, 0, 0);
    bf16x8 a1 = *(const bf16x8*)(pp + (ks + 1) * 32);
    bf16x8 v1 = *(const bf16x8*)(pv + (ks + 1) * 32);
    o1 = __builtin_amdgcn_mfma_f32_16x16x32_bf16(a1, v1, o1, 0, 0, 0);
  }
  // C: row(q) = quad*4+r, col(d) = l15
#pragma unroll
  for (int r = 0; r < 4; ++r) {
    const int q = q0 + quad * 4 + r;
    ao[((long long)(brow + q)) * EE + h * DD + d0 + l15] =
        __float2bfloat16(o0[r] + o1[r]);
  }
}

// ---------------------------------------------------------------------------
extern "C" void kernel_launch(void* const* d_in, const int* in_sizes, int n_in,
                              void* d_out, int out_size, void* d_ws, size_t ws_size,
                              hipStream_t stream) {
  const float* x     = (const float*)d_in[0];  // [4,1024,1024]
  const float* Wqkv  = (const float*)d_in[1];  // [3072,1024]
  const float* bqkv  = (const float*)d_in[2];  // [3072]
  const float* Wproj = (const float*)d_in[3];  // [1024,1024]
  const float* bproj = (const float*)d_in[4];  // [1024]

  float* out   = (float*)d_out;                        // 4M floats
  float* attnF = out + (size_t)BB * SS * EE;           // 64M floats

  const size_t M1 = 1024 * 1024;
  __hip_bfloat16* w = (__hip_bfloat16*)d_ws;

  if (ws_size >= (size_t)80 * 1024 * 1024) {
    // flat: 39M bf16 elems = 78MB
    __hip_bfloat16 *xh = w, *xl = xh + 4 * M1;
    __hip_bfloat16 *Wqh = xl + 4 * M1, *Wql = Wqh + 3 * M1, *Wph = Wql + 3 * M1;
    __hip_bfloat16 *qh = Wph + M1, *ql = qh + 4 * M1, *kh = ql + 4 * M1, *kl = kh + 4 * M1;
    __hip_bfloat16 *vT = kl + 4 * M1, *ao = vT + 4 * M1;

    split_f32<<<4096, 256, 0, stream>>>(x, xh, xl, 1024 * 1024);
    split_f32<<<3072, 256, 0, stream>>>(Wqkv, Wqh, Wql, 768 * 1024);
    split_f32<<<1024, 256, 0, stream>>>(Wproj, Wph, nullptr, 256 * 1024);

    gemm<0><<<dim3(24, 32, 1), 256, 0, stream>>>(
        xh, xl, Wqh, Wql, nullptr, bqkv, nullptr, qh, ql, kh, kl, vT,
        4096, 3072, 1024, 1024, 1024, 0LL, 0LL);
    fused_attn<<<dim3(BB * HH * 64), 256, 0, stream>>>(
        qh, ql, kh, kl, vT, attnF, ao);
    gemm<3><<<dim3(8, 32, 1), 256, 0, stream>>>(
        ao, nullptr, Wph, nullptr, nullptr, bproj, out, nullptr, nullptr, nullptr, nullptr, nullptr,
        4096, 1024, 1024, 1024, 1024, 0LL, 0LL);
    return;
  }

  // per-batch: 7M shared + 8M per-batch = 15M elems = 30MB
  __hip_bfloat16 *Wqh = w, *Wql = Wqh + 3 * M1, *Wph = Wql + 3 * M1;
  __hip_bfloat16 *xh = Wph + M1, *xl = xh + M1;
  __hip_bfloat16 *qh = xl + M1, *ql = qh + M1, *kh = ql + M1, *kl = kh + M1;
  __hip_bfloat16 *vT = kl + M1, *ao = vT + M1;

  split_f32<<<3072, 256, 0, stream>>>(Wqkv, Wqh, Wql, 768 * 1024);
  split_f32<<<1024, 256, 0, stream>>>(Wproj, Wph, nullptr, 256 * 1024);

  for (int b = 0; b < BB; ++b) {
    const float* xb   = x + (size_t)b * SS * EE;
    float* attnb      = attnF + (size_t)b * HH * SS * SS;
    float* outb       = out + (size_t)b * SS * EE;

    split_f32<<<1024, 256, 0, stream>>>(xb, xh, xl, 256 * 1024);
    gemm<0><<<dim3(24, 8, 1), 256, 0, stream>>>(
        xh, xl, Wqh, Wql, nullptr, bqkv, nullptr, qh, ql, kh, kl, vT,
        1024, 3072, 1024, 1024, 1024, 0LL, 0LL);
    fused_attn<<<dim3(HH * 64), 256, 0, stream>>>(
        qh, ql, kh, kl, vT, attnb, ao);
    gemm<3><<<dim3(8, 8, 1), 256, 0, stream>>>(
        ao, nullptr, Wph, nullptr, nullptr, bproj, outb, nullptr, nullptr, nullptr, nullptr, nullptr,
        1024, 1024, 1024, 1024, 1024, 0LL, 0LL);
  }
}

// Round 3
// 668.935 us; speedup vs baseline: 1.1228x; 1.0338x over previous
//
#include <hip/hip_runtime.h>
#include <hip/hip_bf16.h>
#include <cstdint>

// B=4, S=1024, E=1024, H=16, D=64.
// d_out = [ out (4M floats) | filtered_attn (64M floats) ].
// Pipeline: split_f32 -> gemm<0> (QKV proj, split-bf16) -> fused_attn
// (QK^T + softmax/filter + PV; logits REGISTER-resident; 8 waves/block)
// -> gemm<3> (out proj).

#define BB 4
#define SS 1024
#define EE 1024
#define HH 16
#define DD 64

typedef __attribute__((ext_vector_type(8))) short bf16x8;
typedef __attribute__((ext_vector_type(4))) float f32x4;

// ---------------------------------------------------------------------------
// split cast: hi = bf16(v), lo = bf16(v - hi). lo may be null (plain cast).
// ---------------------------------------------------------------------------
__global__ __launch_bounds__(256) void split_f32(
    const float* __restrict__ in, __hip_bfloat16* __restrict__ hi,
    __hip_bfloat16* __restrict__ lo, int n4) {
  int i = blockIdx.x * 256 + threadIdx.x;
  if (i >= n4) return;
  float4 v = ((const float4*)in)[i];
  float vv[4] = {v.x, v.y, v.z, v.w};
  __hip_bfloat16 h[4], l[4];
#pragma unroll
  for (int j = 0; j < 4; ++j) {
    h[j] = __float2bfloat16(vv[j]);
    l[j] = __float2bfloat16(vv[j] - __bfloat162float(h[j]));
  }
  ((ushort4*)hi)[i] = *(ushort4*)h;
  if (lo) ((ushort4*)lo)[i] = *(ushort4*)l;
}

// ---------------------------------------------------------------------------
// NT GEMM: C[m][n] = sum_k A[m*lda+k]*B[n*ldb+k]. 128x128 tile, BK=64,
// 4 waves (2x2), 4x4 x 16x16x32 bf16 MFMA per wave.
// MODE 0 (SPLIT): A=(xh,xl) B=(Wqh,Wql); +bias(f32); out: qh,ql,kh,kl [B,H,S,D], vT [B,H,D,S]
// MODE 3: A=ao B=Wproj_h; +bias(f32); out fp32 oF[m*E+n]
// ---------------------------------------------------------------------------
template <int MODE>
__global__ __launch_bounds__(256) void gemm(
    const __hip_bfloat16* __restrict__ Ah, const __hip_bfloat16* __restrict__ Al,
    const __hip_bfloat16* __restrict__ Bh, const __hip_bfloat16* __restrict__ Bl,
    const float* __restrict__ Af, const float* __restrict__ bias,
    float* __restrict__ oF, __hip_bfloat16* __restrict__ o1,
    __hip_bfloat16* __restrict__ o2, __hip_bfloat16* __restrict__ o3,
    __hip_bfloat16* __restrict__ o4, __hip_bfloat16* __restrict__ o5,
    int M, int N, int K, int lda, int ldb, long long sA, long long sB) {
  constexpr bool SPLIT = (MODE == 0 || MODE == 1);
  constexpr bool AF32  = (MODE == 2);

  const int tid  = threadIdx.x;
  const int lane = tid & 63;
  const int wave = tid >> 6;
  const int wm   = (wave >> 1) * 64;
  const int wn   = (wave & 1) * 64;
  const int quad = lane >> 4;
  const int l15  = lane & 15;
  const int m0   = blockIdx.y * 128;
  const int n0   = blockIdx.x * 128;
  const long long zz = blockIdx.z;

  if (AF32) Af += zz * sA;
  else { Ah += zz * sA; if (SPLIT) Al += zz * sA; }
  Bh += zz * sB;
  if (SPLIT) Bl += zz * sB;

  __shared__ __align__(16) __hip_bfloat16 lds[(SPLIT ? 4 : 2) * 128 * 72];
  __hip_bfloat16* lAh = lds;
  __hip_bfloat16* lAl = SPLIT ? lds + 128 * 72 : nullptr;
  __hip_bfloat16* lBh = lds + (SPLIT ? 2 : 1) * 128 * 72;
  __hip_bfloat16* lBl = SPLIT ? lds + 3 * 128 * 72 : nullptr;

  f32x4 acc[4][4] = {};

  for (int k0 = 0; k0 < K; k0 += 64) {
#pragma unroll
    for (int it = 0; it < 4; ++it) {
      int flat = (it * 256 + tid) * 8;
      int row  = flat >> 6;
      int kk   = flat & 63;
      const bool mok = (m0 + row < M);
      const bool nok = (n0 + row < N);
      if (AF32) {
        float4 f0 = {0, 0, 0, 0}, f1 = {0, 0, 0, 0};
        if (mok) {
          const float* src = Af + (long long)(m0 + row) * lda + k0 + kk;
          f0 = *(const float4*)src;
          f1 = *(const float4*)(src + 4);
        }
        __hip_bfloat16 t[8];
        t[0] = __float2bfloat16(f0.x); t[1] = __float2bfloat16(f0.y);
        t[2] = __float2bfloat16(f0.z); t[3] = __float2bfloat16(f0.w);
        t[4] = __float2bfloat16(f1.x); t[5] = __float2bfloat16(f1.y);
        t[6] = __float2bfloat16(f1.z); t[7] = __float2bfloat16(f1.w);
        *(uint4*)&lAh[row * 72 + kk] = *(uint4*)t;
      } else {
        uint4 va = {0, 0, 0, 0};
        if (mok) va = *(const uint4*)(Ah + (long long)(m0 + row) * lda + k0 + kk);
        *(uint4*)&lAh[row * 72 + kk] = va;
        if (SPLIT) {
          uint4 vl = {0, 0, 0, 0};
          if (mok) vl = *(const uint4*)(Al + (long long)(m0 + row) * lda + k0 + kk);
          *(uint4*)&lAl[row * 72 + kk] = vl;
        }
      }
      uint4 vb = {0, 0, 0, 0};
      if (nok) vb = *(const uint4*)(Bh + (long long)(n0 + row) * ldb + k0 + kk);
      *(uint4*)&lBh[row * 72 + kk] = vb;
      if (SPLIT) {
        uint4 vbl = {0, 0, 0, 0};
        if (nok) vbl = *(const uint4*)(Bl + (long long)(n0 + row) * ldb + k0 + kk);
        *(uint4*)&lBl[row * 72 + kk] = vbl;
      }
    }
    __syncthreads();

#pragma unroll
    for (int ks = 0; ks < 64; ks += 32) {
      bf16x8 ah[4], bh[4], al[4], bl[4];
#pragma unroll
      for (int i = 0; i < 4; ++i) {
        int off = (wm + i * 16 + l15) * 72 + ks + quad * 8;
        ah[i] = *(const bf16x8*)&lAh[off];
        if (SPLIT) al[i] = *(const bf16x8*)&lAl[off];
      }
#pragma unroll
      for (int j = 0; j < 4; ++j) {
        int off = (wn + j * 16 + l15) * 72 + ks + quad * 8;
        bh[j] = *(const bf16x8*)&lBh[off];
        if (SPLIT) bl[j] = *(const bf16x8*)&lBl[off];
      }
#pragma unroll
      for (int i = 0; i < 4; ++i)
#pragma unroll
        for (int j = 0; j < 4; ++j) {
          if (SPLIT) {
            acc[i][j] = __builtin_amdgcn_mfma_f32_16x16x32_bf16(al[i], bh[j], acc[i][j], 0, 0, 0);
            acc[i][j] = __builtin_amdgcn_mfma_f32_16x16x32_bf16(ah[i], bl[j], acc[i][j], 0, 0, 0);
          }
          acc[i][j] = __builtin_amdgcn_mfma_f32_16x16x32_bf16(ah[i], bh[j], acc[i][j], 0, 0, 0);
        }
    }
    __syncthreads();
  }

  // C/D layout: col = lane&15, row = quad*4 + reg
#pragma unroll
  for (int i = 0; i < 4; ++i) {
#pragma unroll
    for (int j = 0; j < 4; ++j) {
#pragma unroll
      for (int r = 0; r < 4; ++r) {
        int m = m0 + wm + i * 16 + quad * 4 + r;
        int n = n0 + wn + j * 16 + l15;
        float v = acc[i][j][r];
        if (MODE == 0) {
          v += bias[n];
          int c = n >> 10, nn = n & 1023, h = nn >> 6, d = nn & 63;
          int b = m >> 10, s = m & 1023;
          long long idx = (((long long)(b * HH + h) * SS + s) << 6) + d;
          if (c == 0) {
            __hip_bfloat16 hh = __float2bfloat16(v);
            o1[idx] = hh;
            o2[idx] = __float2bfloat16(v - __bfloat162float(hh));
          } else if (c == 1) {
            __hip_bfloat16 hh = __float2bfloat16(v);
            o3[idx] = hh;
            o4[idx] = __float2bfloat16(v - __bfloat162float(hh));
          } else {
            o5[(((long long)(b * HH + h) * DD + d) << 10) + s] = __float2bfloat16(v);
          }
        } else if (MODE == 1) {
          oF[zz * (SS * SS) + (long long)m * SS + n] = v * 0.125f;
        } else if (MODE == 2) {
          if (n < DD) {
            int b = (int)(zz >> 4), h = (int)(zz & 15);
            o1[(((long long)(b * SS + m)) << 10) + h * DD + n] = __float2bfloat16(v);
          }
        } else {
          oF[(long long)m * EE + n] = v + bias[n];
        }
      }
    }
  }
}

// ---------------------------------------------------------------------------
// 16-lane-group reductions (lanes quad*16 .. quad*16+15; xor<=8 stays in group)
// ---------------------------------------------------------------------------
__device__ __forceinline__ float qg_max16(float v) {
#pragma unroll
  for (int o = 8; o > 0; o >>= 1) v = fmaxf(v, __shfl_xor(v, o));
  return v;
}
__device__ __forceinline__ float qg_sum16(float v) {
#pragma unroll
  for (int o = 8; o > 0; o >>= 1) v += __shfl_xor(v, o);
  return v;
}

// ---------------------------------------------------------------------------
// fused_attn v3: one block per (bh, 16-row Q strip). 8 waves / 512 threads.
// Phase 1: wave w owns k-cols [w*128, w*128+128) -> acc[8] f32x4 (32 VGPR).
//   lane (quad,l15) holds (q=quad*4+r, k=w*128+nt*16+l15).
// Softmax: lane-local over nt -> l15-group shfl -> cross-wave LDS combine
//   (red[3][8][16], 1.5 KB). Filter division-free: sel = e > 4e-4*Z;
//   P = sel ? e*(1/Zs) : 0. attn written once via NONTEMPORAL f32 stores
//   (write stream bypasses L2 so K/V stay resident); bf16 P -> LDS Pl.
// Phase 3: wave w -> d-group (w&3)*16, k-half (w>>2)*512. 16 MFMA per wave,
//   partial O exchanged via Obuf[4][16][18] (4.6 KB), waves 0-3 finalize.
// LDS 39.2 KB; __launch_bounds__(512,6) -> VGPR<=85 -> 3 blocks/CU
//   = 24 waves/CU (75% occ) vs v2's 16. s_setprio(1) brackets MFMA clusters.
// ---------------------------------------------------------------------------
__global__ __launch_bounds__(512, 6) void fused_attn(
    const __hip_bfloat16* __restrict__ qh, const __hip_bfloat16* __restrict__ ql,
    const __hip_bfloat16* __restrict__ kh, const __hip_bfloat16* __restrict__ kl,
    const __hip_bfloat16* __restrict__ vT, float* __restrict__ attn,
    __hip_bfloat16* __restrict__ ao) {
  const int tid  = threadIdx.x;
  const int lane = tid & 63;
  const int wave = tid >> 6;   // 0..7
  const int quad = lane >> 4;
  const int l15  = lane & 15;

  // XCD-chunked swizzle (gridDim.x is a multiple of 8 -> bijective)
  int id = blockIdx.x;
  const int q8 = gridDim.x >> 3;
  id = (id & 7) * q8 + (id >> 3);
  const int bh = id >> 6;
  const int q0 = (id & 63) * 16;

  const int brow = (bh >> 4) * SS;   // 0 in per-batch mode (bh = h < 16)
  const int h    = bh & 15;
  const long long qbase = ((long long)bh * SS + q0) * DD;
  const long long kbase = (long long)bh * SS * DD;
  const long long vbase = (long long)bh * DD * SS;
  const long long abase = ((long long)bh * SS + q0) * SS;

  __shared__ __align__(16) __hip_bfloat16 Pl[16][1032];  // 33,024 B
  __shared__ float red[3][8][16];                        // 1,536 B
  __shared__ float Obuf[4][16][18];                      // 4,608 B

  // --- Q A-frags (row l15, k-cols quad*8 (+32)), hi & lo ---
  bf16x8 aqh0, aqh1, aql0, aql1;
  {
    const __hip_bfloat16* ph = qh + qbase + l15 * DD + quad * 8;
    const __hip_bfloat16* pl = ql + qbase + l15 * DD + quad * 8;
    aqh0 = *(const bf16x8*)(ph);
    aqh1 = *(const bf16x8*)(ph + 32);
    aql0 = *(const bf16x8*)(pl);
    aql1 = *(const bf16x8*)(pl + 32);
  }

  // --- Phase 1: QK^T, register-resident; wave owns k in [wave*128,+128) ---
  f32x4 acc[8];
  const __hip_bfloat16* pkh0 = kh + kbase + (long long)(wave * 128 + l15) * DD + quad * 8;
  const __hip_bfloat16* pkl0 = kl + kbase + (long long)(wave * 128 + l15) * DD + quad * 8;
#pragma unroll
  for (int nt = 0; nt < 8; ++nt) {
    const __hip_bfloat16* pkh = pkh0 + nt * 16 * DD;
    const __hip_bfloat16* pkl = pkl0 + nt * 16 * DD;
    bf16x8 b0 = *(const bf16x8*)(pkh);
    bf16x8 b1 = *(const bf16x8*)(pkh + 32);
    bf16x8 c0 = *(const bf16x8*)(pkl);
    bf16x8 c1 = *(const bf16x8*)(pkl + 32);
    f32x4 a = {};
    __builtin_amdgcn_s_setprio(1);
    a = __builtin_amdgcn_mfma_f32_16x16x32_bf16(aql0, b0, a, 0, 0, 0);
    a = __builtin_amdgcn_mfma_f32_16x16x32_bf16(aqh0, c0, a, 0, 0, 0);
    a = __builtin_amdgcn_mfma_f32_16x16x32_bf16(aqh0, b0, a, 0, 0, 0);
    a = __builtin_amdgcn_mfma_f32_16x16x32_bf16(aql1, b1, a, 0, 0, 0);
    a = __builtin_amdgcn_mfma_f32_16x16x32_bf16(aqh1, c1, a, 0, 0, 0);
    a = __builtin_amdgcn_mfma_f32_16x16x32_bf16(aqh1, b1, a, 0, 0, 0);
    __builtin_amdgcn_s_setprio(0);
    acc[nt] = a;
  }

  // scale by 1/8 (D=64 -> D^-0.5)
#pragma unroll
  for (int nt = 0; nt < 8; ++nt)
#pragma unroll
    for (int r = 0; r < 4; ++r) acc[nt][r] *= 0.125f;

  // --- row max: lane-local over nt -> l15-group -> cross-wave ---
  float mx[4];
#pragma unroll
  for (int r = 0; r < 4; ++r) {
    float mm = acc[0][r];
#pragma unroll
    for (int nt = 1; nt < 8; ++nt) mm = fmaxf(mm, acc[nt][r]);
    mx[r] = qg_max16(mm);
  }
  if (l15 == 0) {
#pragma unroll
    for (int r = 0; r < 4; ++r) red[0][wave][quad * 4 + r] = mx[r];
  }
  __syncthreads();
  float m[4];
#pragma unroll
  for (int r = 0; r < 4; ++r) {
    const int q = quad * 4 + r;
    float a01 = fmaxf(red[0][0][q], red[0][1][q]);
    float a23 = fmaxf(red[0][2][q], red[0][3][q]);
    float a45 = fmaxf(red[0][4][q], red[0][5][q]);
    float a67 = fmaxf(red[0][6][q], red[0][7][q]);
    m[r] = fmaxf(fmaxf(a01, a23), fmaxf(a45, a67));
  }

  // --- e = exp(v - m), Z ---
  float zl[4] = {0.f, 0.f, 0.f, 0.f};
#pragma unroll
  for (int nt = 0; nt < 8; ++nt)
#pragma unroll
    for (int r = 0; r < 4; ++r) {
      float e = expf(acc[nt][r] - m[r]);
      acc[nt][r] = e;
      zl[r] += e;
    }
#pragma unroll
  for (int r = 0; r < 4; ++r) zl[r] = qg_sum16(zl[r]);
  if (l15 == 0) {
#pragma unroll
    for (int r = 0; r < 4; ++r) red[1][wave][quad * 4 + r] = zl[r];
  }
  __syncthreads();
  float c[4];
#pragma unroll
  for (int r = 0; r < 4; ++r) {
    const int q = quad * 4 + r;
    const float Z = ((red[1][0][q] + red[1][1][q]) + (red[1][2][q] + red[1][3][q])) +
                    ((red[1][4][q] + red[1][5][q]) + (red[1][6][q] + red[1][7][q]));
    c[r] = 4e-4f * Z;   // sel: e > c  <=>  e/Z > 4e-4
  }

  // --- Zs = sum of selected e ---
  float sl[4] = {0.f, 0.f, 0.f, 0.f};
#pragma unroll
  for (int nt = 0; nt < 8; ++nt)
#pragma unroll
    for (int r = 0; r < 4; ++r)
      if (acc[nt][r] > c[r]) sl[r] += acc[nt][r];
#pragma unroll
  for (int r = 0; r < 4; ++r) sl[r] = qg_sum16(sl[r]);
  if (l15 == 0) {
#pragma unroll
    for (int r = 0; r < 4; ++r) red[2][wave][quad * 4 + r] = sl[r];
  }
  __syncthreads();
  float rinv[4];
#pragma unroll
  for (int r = 0; r < 4; ++r) {
    const int q = quad * 4 + r;
    const float Zs = ((red[2][0][q] + red[2][1][q]) + (red[2][2][q] + red[2][3][q])) +
                     ((red[2][4][q] + red[2][5][q]) + (red[2][6][q] + red[2][7][q]));
    rinv[r] = 1.0f / Zs;   // row max always selected -> Zs >= 1
  }

  // --- write filtered probs: f32 NT -> global (required), bf16 -> LDS (P) ---
#pragma unroll
  for (int nt = 0; nt < 8; ++nt) {
    const int k = wave * 128 + nt * 16 + l15;
#pragma unroll
    for (int r = 0; r < 4; ++r) {
      const int q = quad * 4 + r;
      const float e = acc[nt][r];
      const float p = (e > c[r]) ? e * rinv[r] : 0.f;
      __builtin_nontemporal_store(p, &attn[abase + (long long)q * SS + k]);
      Pl[q][k] = __float2bfloat16(p);
    }
  }
  __syncthreads();

  // --- Phase 3: PV. wave -> d-group (wave&3)*16, k-half (wave>>2)*512 ---
  const int d0  = (wave & 3) * 16;
  const int kh2 = (wave >> 2) * 512;
  f32x4 o0 = {}, o1 = {};
  const __hip_bfloat16* pv = vT + vbase + (long long)(d0 + l15) * SS + kh2 + quad * 8;
  const __hip_bfloat16* pp = &Pl[l15][kh2] + quad * 8;
#pragma unroll
  for (int ks = 0; ks < 16; ks += 2) {
    bf16x8 a0 = *(const bf16x8*)(pp + ks * 32);
    bf16x8 v0 = *(const bf16x8*)(pv + ks * 32);
    bf16x8 a1 = *(const bf16x8*)(pp + (ks + 1) * 32);
    bf16x8 v1 = *(const bf16x8*)(pv + (ks + 1) * 32);
    __builtin_amdgcn_s_setprio(1);
    o0 = __builtin_amdgcn_mfma_f32_16x16x32_bf16(a0, v0, o0, 0, 0, 0);
    o1 = __builtin_amdgcn_mfma_f32_16x16x32_bf16(a1, v1, o1, 0, 0, 0);
    __builtin_amdgcn_s_setprio(0);
  }
  if (wave >= 4) {
#pragma unroll
    for (int r = 0; r < 4; ++r)
      Obuf[wave & 3][quad * 4 + r][l15] = o0[r] + o1[r];
  }
  __syncthreads();
  if (wave < 4) {
    // C: row(q) = quad*4+r, col(d) = l15
#pragma unroll
    for (int r = 0; r < 4; ++r) {
      const int q = q0 + quad * 4 + r;
      const float v = o0[r] + o1[r] + Obuf[wave][quad * 4 + r][l15];
      ao[((long long)(brow + q)) * EE + h * DD + d0 + l15] = __float2bfloat16(v);
    }
  }
}

// ---------------------------------------------------------------------------
extern "C" void kernel_launch(void* const* d_in, const int* in_sizes, int n_in,
                              void* d_out, int out_size, void* d_ws, size_t ws_size,
                              hipStream_t stream) {
  const float* x     = (const float*)d_in[0];  // [4,1024,1024]
  const float* Wqkv  = (const float*)d_in[1];  // [3072,1024]
  const float* bqkv  = (const float*)d_in[2];  // [3072]
  const float* Wproj = (const float*)d_in[3];  // [1024,1024]
  const float* bproj = (const float*)d_in[4];  // [1024]

  float* out   = (float*)d_out;                        // 4M floats
  float* attnF = out + (size_t)BB * SS * EE;           // 64M floats

  const size_t M1 = 1024 * 1024;
  __hip_bfloat16* w = (__hip_bfloat16*)d_ws;

  if (ws_size >= (size_t)80 * 1024 * 1024) {
    // flat: 39M bf16 elems = 78MB
    __hip_bfloat16 *xh = w, *xl = xh + 4 * M1;
    __hip_bfloat16 *Wqh = xl + 4 * M1, *Wql = Wqh + 3 * M1, *Wph = Wql + 3 * M1;
    __hip_bfloat16 *qh = Wph + M1, *ql = qh + 4 * M1, *kh = ql + 4 * M1, *kl = kh + 4 * M1;
    __hip_bfloat16 *vT = kl + 4 * M1, *ao = vT + 4 * M1;

    split_f32<<<4096, 256, 0, stream>>>(x, xh, xl, 1024 * 1024);
    split_f32<<<3072, 256, 0, stream>>>(Wqkv, Wqh, Wql, 768 * 1024);
    split_f32<<<1024, 256, 0, stream>>>(Wproj, Wph, nullptr, 256 * 1024);

    gemm<0><<<dim3(24, 32, 1), 256, 0, stream>>>(
        xh, xl, Wqh, Wql, nullptr, bqkv, nullptr, qh, ql, kh, kl, vT,
        4096, 3072, 1024, 1024, 1024, 0LL, 0LL);
    fused_attn<<<dim3(BB * HH * 64), 512, 0, stream>>>(
        qh, ql, kh, kl, vT, attnF, ao);
    gemm<3><<<dim3(8, 32, 1), 256, 0, stream>>>(
        ao, nullptr, Wph, nullptr, nullptr, bproj, out, nullptr, nullptr, nullptr, nullptr, nullptr,
        4096, 1024, 1024, 1024, 1024, 0LL, 0LL);
    return;
  }

  // per-batch: 7M shared + 8M per-batch = 15M elems = 30MB
  __hip_bfloat16 *Wqh = w, *Wql = Wqh + 3 * M1, *Wph = Wql + 3 * M1;
  __hip_bfloat16 *xh = Wph + M1, *xl = xh + M1;
  __hip_bfloat16 *qh = xl + M1, *ql = qh + M1, *kh = ql + M1, *kl = kh + M1;
  __hip_bfloat16 *vT = kl + M1, *ao = vT + M1;

  split_f32<<<3072, 256, 0, stream>>>(Wqkv, Wqh, Wql, 768 * 1024);
  split_f32<<<1024, 256, 0, stream>>>(Wproj, Wph, nullptr, 256 * 1024);

  for (int b = 0; b < BB; ++b) {
    const float* xb   = x + (size_t)b * SS * EE;
    float* attnb      = attnF + (size_t)b * HH * SS * SS;
    float* outb       = out + (size_t)b * SS * EE;

    split_f32<<<1024, 256, 0, stream>>>(xb, xh, xl, 256 * 1024);
    gemm<0><<<dim3(24, 8, 1), 256, 0, stream>>>(
        xh, xl, Wqh, Wql, nullptr, bqkv, nullptr, qh, ql, kh, kl, vT,
        1024, 3072, 1024, 1024, 1024, 0LL, 0LL);
    fused_attn<<<dim3(HH * 64), 512, 0, stream>>>(
        qh, ql, kh, kl, vT, attnb, ao);
    gemm<3><<<dim3(8, 8, 1), 256, 0, stream>>>(
        ao, nullptr, Wph, nullptr, nullptr, bproj, outb, nullptr, nullptr, nullptr, nullptr, nullptr,
        1024, 1024, 1024, 1024, 1024, 0LL, 0LL);
  }
}